// Round 5
// baseline (207.103 us; speedup 1.0000x reference)
//
#include <hip/hip_runtime.h>

// NCC loss, fused single-kernel. Inputs y_true, y_pred: (2,1,160,192,160) FP32.
// Output: ONE FP32 scalar = -sum(cc).
// Dtype forensics (R0-R4): fp32-in/fp32-out is the only assignment consistent
// with all five benches (R4's NaN = bf16-misread of fp32 bit patterns; R2/R3's
// exact-|ref| = 2-byte write into 4-byte slot; R1's finite error = ring-prefill
// off-by-one in the old two-pass code, fixed here by the zero-initialized ring).
#define ND 2
#define DD 160
#define HH 192
#define WW 160
#define HW (HH * WW)
#define DHW (DD * HH * WW)

constexpr int TW    = 16;   // tile width (output pixels)
constexpr int TH    = 16;   // tile height
constexpr int WLO   = TW + 8;              // 24 incl. W halo
constexpr int HLO   = TH + 8;              // 24 incl. H halo
constexpr int CHUNK = 40;   // output d's per block
constexpr int NCH   = DD / CHUNK;          // 4
constexpr int NSL   = CHUNK + 8;           // 48 slices per block

__global__ __launch_bounds__(256)
void ncc_fused(const float* __restrict__ I,
               const float* __restrict__ J,
               float* __restrict__ outp)
{
    __shared__ float sI[HLO][WLO];
    __shared__ float sJ[HLO][WLO];
    __shared__ float sw[5][HLO][TW];   // W-summed products, rows incl. H halo
    __shared__ float wsum[4];

    const int tid = threadIdx.x;
    const int w0  = blockIdx.x * TW;
    const int h0  = blockIdx.y * TH;
    const int z   = blockIdx.z;             // n * NCH + chunk
    const int n   = z / NCH;
    const int d0  = (z % NCH) * CHUNK;

    const int h = tid / TW;                 // this thread's output pixel
    const int w = tid % TW;

    float rbuf[5][9];
    #pragma unroll
    for (int p = 0; p < 5; ++p)
        #pragma unroll
        for (int j = 0; j < 9; ++j) rbuf[p][j] = 0.f;
    float run[5] = {0.f, 0.f, 0.f, 0.f, 0.f};
    float acc = 0.f;

    const float inv = 1.0f / 729.0f;

    #pragma unroll 1
    for (int g = 0; g < 6; ++g) {           // 6 x 9 = 54 >= NSL
        #pragma unroll
        for (int jj = 0; jj < 9; ++jj) {
            const int s = g * 9 + jj;       // uniform across block
            if (s < NSL) {
                const int dd = d0 - 4 + s;  // slice entering the window
                const bool dok = (dd >= 0) && (dd < DD);
                const long long slice = (long long)(n * DD + dd) * HW;

                // ---- stage raw fp32 slice tile (zero-padded halo) ----
                for (int idx = tid; idx < HLO * WLO; idx += 256) {
                    const int hh = idx / WLO, ww = idx % WLO;
                    const int gh = h0 + hh - 4, gw = w0 + ww - 4;
                    float vi = 0.f, vj = 0.f;
                    if (dok && gh >= 0 && gh < HH && gw >= 0 && gw < WW) {
                        const long long gg = slice + (long long)gh * WW + gw;
                        vi = I[gg];
                        vj = J[gg];
                    }
                    sI[hh][ww] = vi;
                    sJ[hh][ww] = vj;
                }
                __syncthreads();

                // ---- 9-tap W-sums of the five products ----
                for (int pos = tid; pos < HLO * TW; pos += 256) {
                    const int hh = pos / TW, wq = pos % TW;
                    float s0 = 0.f, s1 = 0.f, s2 = 0.f, s3 = 0.f, s4 = 0.f;
                    #pragma unroll
                    for (int k = 0; k < 9; ++k) {
                        const float a = sI[hh][wq + k];
                        const float b = sJ[hh][wq + k];
                        s0 += a; s1 += b;
                        s2 += a * a; s3 += b * b; s4 += a * b;
                    }
                    sw[0][hh][wq] = s0;
                    sw[1][hh][wq] = s1;
                    sw[2][hh][wq] = s2;
                    sw[3][hh][wq] = s3;
                    sw[4][hh][wq] = s4;
                }
                __syncthreads();

                // ---- 9-tap H-sum at (h,w), D-ring update, cc ----
                float S[5];
                #pragma unroll
                for (int p = 0; p < 5; ++p) {
                    float t = 0.f;
                    #pragma unroll
                    for (int j = 0; j < 9; ++j) t += sw[p][h + j][w];
                    S[p] = t;
                }
                #pragma unroll
                for (int p = 0; p < 5; ++p) {
                    run[p] += S[p] - rbuf[p][jj];   // slot static after unroll
                    rbuf[p][jj] = S[p];
                }

                if (s >= 8) {                        // window [d-4,d+4] full
                    const float Is = run[0], Js = run[1];
                    const float I2 = run[2], J2 = run[3], IJ = run[4];
                    const float uI = Is * inv, uJ = Js * inv;
                    const float cross = IJ - uI * Js;
                    const float Iv = fmaxf(I2 - uI * Is, 1e-5f);
                    const float Jv = fmaxf(J2 - uJ * Js, 1e-5f);
                    acc += cross * cross / (Iv * Jv + 1e-5f);
                }
            }
        }
    }

    // ---- block reduction, one fp32 atomic per block ----
    #pragma unroll
    for (int off = 32; off > 0; off >>= 1)
        acc += __shfl_down(acc, off, 64);
    const int lane = tid & 63, wid = tid >> 6;
    if (lane == 0) wsum[wid] = acc;
    __syncthreads();
    if (tid == 0)
        atomicAdd(outp, -(wsum[0] + wsum[1] + wsum[2] + wsum[3]));
}

extern "C" void kernel_launch(void* const* d_in, const int* in_sizes, int n_in,
                              void* d_out, int out_size, void* d_ws, size_t ws_size,
                              hipStream_t stream)
{
    const float* I = (const float*)d_in[0];   // y_true
    const float* J = (const float*)d_in[1];   // y_pred
    float* out = (float*)d_out;

    // d_out is re-poisoned before every timed launch -> zero it on-stream,
    // then accumulate -sum(cc) directly into out[0].
    hipMemsetAsync(out, 0, sizeof(float), stream);

    dim3 grid(WW / TW, HH / TH, ND * NCH);   // 10 x 12 x 8 = 960 blocks
    ncc_fused<<<grid, 256, 0, stream>>>(I, J, out);
}